// Round 8
// baseline (237.852 us; speedup 1.0000x reference)
//
#include <hip/hip_runtime.h>
#include <hip/hip_fp16.h>

#define NN 50000
#define NE 800000
#define NG 512
#define DD 128
#define NSB 64               // sub-bins == subpartitions (one wg each)
#define SUBN 782             // ceil(NN/NSB); 64*782 = 50048
#define SBCAP 14336          // per-sub-bin capacity (mean 12500, sigma 111)
#define NB1 512
#define CHUNK ((NE + NB1 - 1) / NB1)   // 1563

typedef __attribute__((ext_vector_type(8))) _Float16 f16x8;
typedef __attribute__((ext_vector_type(4))) float f32x4;

// ---- P0: features f32 -> fp16 ----
__global__ __launch_bounds__(256) void k_f2h(
    const float4* __restrict__ in, uint2* __restrict__ out, int n4) {
  int i = blockIdx.x * 256 + threadIdx.x;
  if (i >= n4) return;
  float4 v = in[i];
  __half2 a = __floats2half2_rn(v.x, v.y);
  __half2 b = __floats2half2_rn(v.z, v.w);
  uint2 o;
  o.x = *(unsigned int*)&a;
  o.y = *(unsigned int*)&b;
  out[i] = o;
}

// ---- W split (f32 -> fp16 hi + fp16 residual), packed in MFMA B-fragment
// order: idx = ((nt*4+kk)*64 + lane)*8 + j holds W[kk*32+(lane>>4)*8+j][nt*16+(lane&15)].
__global__ __launch_bounds__(256) void k_wsplit(
    const float* __restrict__ W, _Float16* __restrict__ hi, _Float16* __restrict__ lo) {
  int t = blockIdx.x * 256 + threadIdx.x;   // 0..2047
  int lane = t & 63;
  int grp = t >> 6;        // nt*4+kk
  int kk = grp & 3;
  int nt = grp >> 2;
  int kbase = kk * 32 + ((lane >> 4) << 3);
  int c = nt * 16 + (lane & 15);
#pragma unroll
  for (int j = 0; j < 8; ++j) {
    float v = W[(kbase + j) * DD + c];
    _Float16 h = (_Float16)v;
    hi[t * 8 + j] = h;
    lo[t * 8 + j] = (_Float16)(v - (float)h);
  }
}

// ---- P1: bin edges into 64 sub-bins (dst-keyed (d,s) u64; src-keyed u32). ----
__global__ __launch_bounds__(256) void k_bin(
    const int* __restrict__ src, const int* __restrict__ dst,
    int* __restrict__ cur_d, int* __restrict__ cur_s,
    unsigned long long* __restrict__ byDst, int* __restrict__ bySrc) {
  __shared__ int cntd[NSB], cnts[NSB], based[NSB], bases[NSB];
  int e0 = blockIdx.x * CHUNK;
  int e1 = e0 + CHUNK; if (e1 > NE) e1 = NE;
  int tid = threadIdx.x;
  if (tid < NSB) { cntd[tid] = 0; cnts[tid] = 0; }
  __syncthreads();
  for (int e = e0 + tid; e < e1; e += 256) {
    atomicAdd(&cntd[dst[e] / SUBN], 1);
    atomicAdd(&cnts[src[e] / SUBN], 1);
  }
  __syncthreads();
  if (tid < NSB) {
    based[tid] = atomicAdd(&cur_d[tid], cntd[tid]);
    cntd[tid] = 0;
  } else if (tid < 2 * NSB) {
    int b = tid - NSB;
    bases[b] = atomicAdd(&cur_s[b], cnts[b]);
    cnts[b] = 0;
  }
  __syncthreads();
  for (int e = e0 + tid; e < e1; e += 256) {
    int d = dst[e], s = src[e];
    int bd = d / SUBN;
    int pd = based[bd] + atomicAdd(&cntd[bd], 1);
    if (pd < SBCAP) byDst[(size_t)bd * SBCAP + pd] = ((unsigned long long)(unsigned)d << 32) | (unsigned)s;
    int bs = s / SUBN;
    int ps = bases[bs] + atomicAdd(&cnts[bs], 1);
    if (ps < SBCAP) bySrc[(size_t)bs * SBCAP + ps] = s;
  }
}

// ---- P2a: per-sub-bin histogram + scan + CSR scatter. No global atomics. ----
__global__ __launch_bounds__(1024) void k_csr_dst(
    const unsigned long long* __restrict__ byDst, const int* __restrict__ cur_d,
    int* __restrict__ csr, int* __restrict__ row_start, int* __restrict__ deg_in) {
  int q = blockIdx.x;
  int nlo = q * SUBN;
  int nhi = nlo + SUBN; if (nhi > NN) nhi = NN;
  int nloc = nhi - nlo;
  __shared__ int hist[SUBN];
  __shared__ int wsum[16];
  int tid = threadIdx.x;
  for (int i = tid; i < SUBN; i += 1024) hist[i] = 0;
  __syncthreads();
  int m = cur_d[q];
  if (m > SBCAP) m = SBCAP;
  const unsigned long long* bine = byDst + (size_t)q * SBCAP;
  for (int i = tid; i < m; i += 1024) {
    int l = (int)(bine[i] >> 32) - nlo;
    if (l >= 0 && l < nloc) atomicAdd(&hist[l], 1);
  }
  __syncthreads();
  int v = (tid < SUBN) ? hist[tid] : 0;
  int incl = v;
  int lane = tid & 63;
#pragma unroll
  for (int off = 1; off < 64; off <<= 1) {
    int t2 = __shfl_up(incl, off);
    if (lane >= off) incl += t2;
  }
  int wid = tid >> 6;
  if (lane == 63) wsum[wid] = incl;
  __syncthreads();
  if (tid == 0) {
    int run = 0;
    for (int i = 0; i < 16; ++i) { int t = wsum[i]; wsum[i] = run; run += t; }
  }
  __syncthreads();
  int excl = incl - v + wsum[wid];
  if (tid < nloc) {
    deg_in[nlo + tid] = v;
    row_start[nlo + tid] = q * SBCAP + excl;
  }
  __syncthreads();
  if (tid < SUBN) hist[tid] = excl;   // scatter cursor
  __syncthreads();
  for (int i = tid; i < m; i += 1024) {
    unsigned long long p = bine[i];
    int l = (int)(p >> 32) - nlo;
    if (l >= 0 && l < nloc) {
      int pos = atomicAdd(&hist[l], 1);
      if (pos < SBCAP) csr[(size_t)q * SBCAP + pos] = (int)(unsigned)p;
    }
  }
}

// ---- P2b: histogram-only for deg_out ----
__global__ __launch_bounds__(1024) void k_deg_src(
    const int* __restrict__ bySrc, const int* __restrict__ cur_s,
    int* __restrict__ deg_out) {
  int q = blockIdx.x;
  int nlo = q * SUBN;
  int nhi = nlo + SUBN; if (nhi > NN) nhi = NN;
  int nloc = nhi - nlo;
  __shared__ int hist[SUBN];
  int tid = threadIdx.x;
  for (int i = tid; i < SUBN; i += 1024) hist[i] = 0;
  __syncthreads();
  int m = cur_s[q];
  if (m > SBCAP) m = SBCAP;
  const int* bine = bySrc + (size_t)q * SBCAP;
  for (int i = tid; i < m; i += 1024) {
    int l = bine[i] - nlo;
    if (l >= 0 && l < nloc) atomicAdd(&hist[l], 1);
  }
  __syncthreads();
  for (int i = tid; i < nloc; i += 1024) deg_out[nlo + i] = hist[i];
}

// ---- norms ----
__global__ __launch_bounds__(256) void k_norm(
    const int* __restrict__ deg_out, const int* __restrict__ deg_in,
    float* __restrict__ out_norm, float* __restrict__ in_norm) {
  int i = blockIdx.x * 256 + threadIdx.x;
  if (i >= NN) return;
  int od = deg_out[i], idg = deg_in[i];
  out_norm[i] = od > 0 ? rsqrtf((float)od) : 0.f;
  in_norm[i]  = idg > 0 ? rsqrtf((float)idg) : 0.f;
}

// ---- per-graph node counts (gid sorted) ----
__global__ __launch_bounds__(512) void k_cnt(
    const int* __restrict__ gid, int* __restrict__ cnt) {
  int g = blockIdx.x * 512 + threadIdx.x;
  if (g >= NG) return;
  int lo, hi;
  { int a = 0, b = NN; while (a < b) { int m = (a + b) >> 1; if (gid[m] < g) a = m + 1; else b = m; } lo = a; }
  { int a = lo, b = NN; while (a < b) { int m = (a + b) >> 1; if (gid[m] <= g) a = m + 1; else b = m; } hi = a; }
  cnt[g] = hi - lo;
}

// ---- aggregation: one wave per dst node, fp16 row gather, f32 accumulate ----
__global__ __launch_bounds__(256) void k_agg(
    const __half* __restrict__ x, const int* __restrict__ csr,
    const int* __restrict__ row_start, const int* __restrict__ deg_in,
    const float* __restrict__ out_norm, float* __restrict__ agg) {
  int node = blockIdx.x * 4 + (threadIdx.x >> 6);
  int lane = threadIdx.x & 63;
  if (node >= NN) return;
  int n = deg_in[node];
  const int* bk = csr + row_start[node];
  const __half2* xv = (const __half2*)x;
  float2 a0 = {0.f, 0.f}, a1 = {0.f, 0.f}, a2 = {0.f, 0.f}, a3 = {0.f, 0.f};
  for (int c0 = 0; c0 < n; c0 += 64) {
    int nn = n - c0; if (nn > 64) nn = 64;
    int sl = 0; float wl = 0.f;
    if (lane < nn) { sl = bk[c0 + lane]; wl = out_norm[sl]; }
    int j = 0;
    for (; j + 4 <= nn; j += 4) {
      int s0 = __shfl(sl, j + 0), s1 = __shfl(sl, j + 1);
      int s2 = __shfl(sl, j + 2), s3 = __shfl(sl, j + 3);
      float w0 = __shfl(wl, j + 0), w1 = __shfl(wl, j + 1);
      float w2 = __shfl(wl, j + 2), w3 = __shfl(wl, j + 3);
      float2 v0 = __half22float2(xv[(size_t)s0 * 64 + lane]);
      float2 v1 = __half22float2(xv[(size_t)s1 * 64 + lane]);
      float2 v2 = __half22float2(xv[(size_t)s2 * 64 + lane]);
      float2 v3 = __half22float2(xv[(size_t)s3 * 64 + lane]);
      a0.x += v0.x * w0; a0.y += v0.y * w0;
      a1.x += v1.x * w1; a1.y += v1.y * w1;
      a2.x += v2.x * w2; a2.y += v2.y * w2;
      a3.x += v3.x * w3; a3.y += v3.y * w3;
    }
    for (; j < nn; ++j) {
      int s0 = __shfl(sl, j);
      float w0 = __shfl(wl, j);
      float2 v0 = __half22float2(xv[(size_t)s0 * 64 + lane]);
      a0.x += v0.x * w0; a0.y += v0.y * w0;
    }
  }
  a0.x += a1.x + a2.x + a3.x;
  a0.y += a1.y + a2.y + a3.y;
  ((float2*)agg)[(size_t)node * 64 + lane] = a0;
}

// ---- MFMA GEMM: Y[i][c] = act(in_norm[i] * (A@W)[i][c] + b[c]) ----
// Split-fp16: A=A_hi+A_lo, W=W_hi+W_lo; acc = Ah*Wh + Ah*Wl + Al*Wh (f32 MFMA acc).
// POOL: instead of storing Y, compute per-row logits y@Wc (2 cols) via 16-lane
// butterfly and atomically accumulate per-graph sums (mean-pool fused).
template <bool RELU, bool HOUT, bool POOL>
__global__ __launch_bounds__(256) void k_gemm_mfma(
    const float* __restrict__ A, const float* __restrict__ in_norm,
    const _Float16* __restrict__ Whi, const _Float16* __restrict__ Wlo,
    const float* __restrict__ bias, void* __restrict__ Yv,
    const int* __restrict__ gid, const float* __restrict__ Wc,
    float* __restrict__ accg) {
  __shared__ __align__(16) _Float16 lhi[16384];
  __shared__ __align__(16) _Float16 llo[16384];
  int tid = threadIdx.x;
  {
    const uint4* sh = (const uint4*)Whi;
    const uint4* sl = (const uint4*)Wlo;
    uint4* dh = (uint4*)lhi;
    uint4* dl = (uint4*)llo;
#pragma unroll
    for (int i = 0; i < 8; ++i) {
      dh[tid + i * 256] = sh[tid + i * 256];
      dl[tid + i * 256] = sl[tid + i * 256];
    }
  }
  __syncthreads();
  int wid = tid >> 6, lane = tid & 63;
  int row0 = blockIdx.x * 64 + wid * 16;
  int ar = row0 + (lane & 15);
  bool rv = ar < NN;
  f16x8 ahi[4], alo[4];
#pragma unroll
  for (int kk = 0; kk < 4; ++kk) {
    float v[8];
    if (rv) {
      const float4* ap = (const float4*)(A + (size_t)ar * DD + kk * 32 + ((lane >> 4) << 3));
      float4 u0 = ap[0], u1 = ap[1];
      v[0] = u0.x; v[1] = u0.y; v[2] = u0.z; v[3] = u0.w;
      v[4] = u1.x; v[5] = u1.y; v[6] = u1.z; v[7] = u1.w;
    } else {
#pragma unroll
      for (int j = 0; j < 8; ++j) v[j] = 0.f;
    }
#pragma unroll
    for (int j = 0; j < 8; ++j) {
      _Float16 h = (_Float16)v[j];
      ahi[kk][j] = h;
      alo[kk][j] = (_Float16)(v[j] - (float)h);
    }
  }
  f32x4 acc[8];
#pragma unroll
  for (int nt = 0; nt < 8; ++nt) acc[nt] = (f32x4){0.f, 0.f, 0.f, 0.f};
#pragma unroll
  for (int nt = 0; nt < 8; ++nt) {
#pragma unroll
    for (int kk = 0; kk < 4; ++kk) {
      f16x8 bh = *(const f16x8*)&lhi[(((nt * 4 + kk) * 64) + lane) * 8];
      f16x8 bl = *(const f16x8*)&llo[(((nt * 4 + kk) * 64) + lane) * 8];
      acc[nt] = __builtin_amdgcn_mfma_f32_16x16x32_f16(ahi[kk], bh, acc[nt], 0, 0, 0);
      acc[nt] = __builtin_amdgcn_mfma_f32_16x16x32_f16(ahi[kk], bl, acc[nt], 0, 0, 0);
      acc[nt] = __builtin_amdgcn_mfma_f32_16x16x32_f16(alo[kk], bh, acc[nt], 0, 0, 0);
    }
  }
  int r4 = (lane >> 4) * 4;
  int c0 = lane & 15;
  if (POOL) {
    float wc0[8], wc1[8];
#pragma unroll
    for (int nt = 0; nt < 8; ++nt) {
      int col = nt * 16 + c0;
      wc0[nt] = Wc[col * 2 + 0];
      wc1[nt] = Wc[col * 2 + 1];
    }
#pragma unroll
    for (int reg = 0; reg < 4; ++reg) {
      int row = row0 + r4 + reg;
      float inm = (row < NN) ? in_norm[row] : 0.f;
      float v0 = 0.f, v1 = 0.f;
#pragma unroll
      for (int nt = 0; nt < 8; ++nt) {
        int col = nt * 16 + c0;
        float y = acc[nt][reg] * inm + bias[col];
        if (RELU) y = fmaxf(y, 0.f);
        v0 += y * wc0[nt];
        v1 += y * wc1[nt];
      }
#pragma unroll
      for (int off = 1; off < 16; off <<= 1) {
        v0 += __shfl_xor(v0, off);
        v1 += __shfl_xor(v1, off);
      }
      if (row < NN && c0 == 0) {
        int g = gid[row];
        atomicAdd(&accg[g * 2 + 0], v0);
        atomicAdd(&accg[g * 2 + 1], v1);
      }
    }
  } else {
#pragma unroll
    for (int reg = 0; reg < 4; ++reg) {
      int row = row0 + r4 + reg;
      if (row < NN) {
        float inm = in_norm[row];
#pragma unroll
        for (int nt = 0; nt < 8; ++nt) {
          int col = nt * 16 + c0;
          float y = acc[nt][reg] * inm + bias[col];
          if (RELU) y = fmaxf(y, 0.f);
          if (HOUT) ((__half*)Yv)[(size_t)row * DD + col] = __float2half(y);
          else      ((float*)Yv)[(size_t)row * DD + col] = y;
        }
      }
    }
  }
}

// ---- finalize: out[g][c] = accg[g][c]/cnt[g] + bc[c] ----
__global__ __launch_bounds__(256) void k_final(
    const float* __restrict__ accg, const int* __restrict__ cnt,
    const float* __restrict__ bc, float* __restrict__ out) {
  int i = blockIdx.x * 256 + threadIdx.x;
  if (i >= NG * 2) return;
  int g = i >> 1, c = i & 1;
  int n = cnt[g];
  out[i] = accg[i] / (float)(n > 0 ? n : 1) + bc[c];
}

extern "C" void kernel_launch(void* const* d_in, const int* in_sizes, int n_in,
                              void* d_out, int out_size, void* d_ws, size_t ws_size,
                              hipStream_t stream) {
  const float* features = (const float*)d_in[0];
  const int* src = (const int*)d_in[1];
  const int* dst = (const int*)d_in[2];
  const int* gid = (const int*)d_in[3];
  const float* W1 = (const float*)d_in[4];
  const float* b1 = (const float*)d_in[5];
  const float* W2 = (const float*)d_in[6];
  const float* b2 = (const float*)d_in[7];
  const float* Wc = (const float*)d_in[8];
  const float* bc = (const float*)d_in[9];
  float* out = (float*)d_out;

  char* ws = (char*)d_ws;
  size_t off = 0;
  auto take = [&](size_t bytes) {
    char* p = ws + off;
    off = (off + bytes + 255) & ~(size_t)255;
    return p;
  };
  int* cur_d      = (int*)take(NSB * 4);
  int* cur_s      = (int*)take(NSB * 4);
  int* deg_out    = (int*)take((size_t)NN * 4);
  int* deg_in     = (int*)take((size_t)NN * 4);
  float* out_nrm  = (float*)take((size_t)NN * 4);
  float* in_nrm   = (float*)take((size_t)NN * 4);
  int* row_start  = (int*)take((size_t)NN * 4);
  int* cntg       = (int*)take((size_t)NG * 4);
  float* accg     = (float*)take((size_t)NG * 2 * 4);
  unsigned long long* byDst = (unsigned long long*)take((size_t)NSB * SBCAP * 8);
  int* bySrc      = (int*)take((size_t)NSB * SBCAP * 4);
  int* csr        = (int*)take((size_t)NSB * SBCAP * 4);
  __half* xh      = (__half*)take((size_t)NN * DD * 2);
  __half* h1h     = (__half*)take((size_t)NN * DD * 2);
  float* bufA     = (float*)take((size_t)NN * DD * 4);
  _Float16* w1hi  = (_Float16*)take((size_t)DD * DD * 2);
  _Float16* w1lo  = (_Float16*)take((size_t)DD * DD * 2);
  _Float16* w2hi  = (_Float16*)take((size_t)DD * DD * 2);
  _Float16* w2lo  = (_Float16*)take((size_t)DD * DD * 2);

  hipMemsetAsync(cur_d, 0, NSB * 4, stream);
  hipMemsetAsync(cur_s, 0, NSB * 4, stream);
  hipMemsetAsync(accg, 0, (size_t)NG * 2 * 4, stream);

  k_f2h<<<(NN * DD / 4 + 255) / 256, 256, 0, stream>>>((const float4*)features, (uint2*)xh, NN * DD / 4);
  k_wsplit<<<8, 256, 0, stream>>>(W1, w1hi, w1lo);
  k_wsplit<<<8, 256, 0, stream>>>(W2, w2hi, w2lo);
  k_bin<<<NB1, 256, 0, stream>>>(src, dst, cur_d, cur_s, byDst, bySrc);
  k_csr_dst<<<NSB, 1024, 0, stream>>>(byDst, cur_d, csr, row_start, deg_in);
  k_deg_src<<<NSB, 1024, 0, stream>>>(bySrc, cur_s, deg_out);
  k_norm<<<(NN + 255) / 256, 256, 0, stream>>>(deg_out, deg_in, out_nrm, in_nrm);
  k_cnt<<<1, 512, 0, stream>>>(gid, cntg);

  // layer 1: agg(xh) -> bufA ; mfma-gemm+relu -> h1h (fp16)
  k_agg<<<(NN + 3) / 4, 256, 0, stream>>>(xh, csr, row_start, deg_in, out_nrm, bufA);
  k_gemm_mfma<true, true, false><<<(NN + 63) / 64, 256, 0, stream>>>(
      bufA, in_nrm, w1hi, w1lo, b1, h1h, nullptr, nullptr, nullptr);

  // layer 2: agg(h1h) -> bufA ; mfma-gemm + fused mean-pool/classify -> accg
  k_agg<<<(NN + 3) / 4, 256, 0, stream>>>(h1h, csr, row_start, deg_in, out_nrm, bufA);
  k_gemm_mfma<false, false, true><<<(NN + 63) / 64, 256, 0, stream>>>(
      bufA, in_nrm, w2hi, w2lo, b2, nullptr, gid, Wc, accg);

  // finalize
  k_final<<<(NG * 2 + 255) / 256, 256, 0, stream>>>(accg, cntg, bc, out);
}

// Round 9
// 171.123 us; speedup vs baseline: 1.3900x; 1.3900x over previous
//
#include <hip/hip_runtime.h>
#include <hip/hip_fp16.h>

#define NN 50000
#define NE 800000
#define NG 512
#define DD 128
#define NSB 64               // sub-bins == subpartitions (one wg each)
#define SUBN 782             // ceil(NN/NSB); 64*782 = 50048
#define SBCAP 14336          // per-sub-bin capacity (mean 12500, sigma 111)
#define NB1 512
#define CHUNK ((NE + NB1 - 1) / NB1)   // 1563

typedef __attribute__((ext_vector_type(8))) _Float16 f16x8;
typedef __attribute__((ext_vector_type(4))) float f32x4;

// ---- P0: features f32 -> fp16 ----
__global__ __launch_bounds__(256) void k_f2h(
    const float4* __restrict__ in, uint2* __restrict__ out, int n4) {
  int i = blockIdx.x * 256 + threadIdx.x;
  if (i >= n4) return;
  float4 v = in[i];
  __half2 a = __floats2half2_rn(v.x, v.y);
  __half2 b = __floats2half2_rn(v.z, v.w);
  uint2 o;
  o.x = *(unsigned int*)&a;
  o.y = *(unsigned int*)&b;
  out[i] = o;
}

// ---- W split (f32 -> fp16 hi + fp16 residual), packed in MFMA B-fragment
// order: idx = ((nt*4+kk)*64 + lane)*8 + j holds W[kk*32+(lane>>4)*8+j][nt*16+(lane&15)].
__global__ __launch_bounds__(256) void k_wsplit(
    const float* __restrict__ W, _Float16* __restrict__ hi, _Float16* __restrict__ lo) {
  int t = blockIdx.x * 256 + threadIdx.x;   // 0..2047
  int lane = t & 63;
  int grp = t >> 6;        // nt*4+kk
  int kk = grp & 3;
  int nt = grp >> 2;
  int kbase = kk * 32 + ((lane >> 4) << 3);
  int c = nt * 16 + (lane & 15);
#pragma unroll
  for (int j = 0; j < 8; ++j) {
    float v = W[(kbase + j) * DD + c];
    _Float16 h = (_Float16)v;
    hi[t * 8 + j] = h;
    lo[t * 8 + j] = (_Float16)(v - (float)h);
  }
}

// ---- P1: bin edges into 64 sub-bins (dst-keyed (d,s) u64; src-keyed u32). ----
__global__ __launch_bounds__(256) void k_bin(
    const int* __restrict__ src, const int* __restrict__ dst,
    int* __restrict__ cur_d, int* __restrict__ cur_s,
    unsigned long long* __restrict__ byDst, int* __restrict__ bySrc) {
  __shared__ int cntd[NSB], cnts[NSB], based[NSB], bases[NSB];
  int e0 = blockIdx.x * CHUNK;
  int e1 = e0 + CHUNK; if (e1 > NE) e1 = NE;
  int tid = threadIdx.x;
  if (tid < NSB) { cntd[tid] = 0; cnts[tid] = 0; }
  __syncthreads();
  for (int e = e0 + tid; e < e1; e += 256) {
    atomicAdd(&cntd[dst[e] / SUBN], 1);
    atomicAdd(&cnts[src[e] / SUBN], 1);
  }
  __syncthreads();
  if (tid < NSB) {
    based[tid] = atomicAdd(&cur_d[tid], cntd[tid]);
    cntd[tid] = 0;
  } else if (tid < 2 * NSB) {
    int b = tid - NSB;
    bases[b] = atomicAdd(&cur_s[b], cnts[b]);
    cnts[b] = 0;
  }
  __syncthreads();
  for (int e = e0 + tid; e < e1; e += 256) {
    int d = dst[e], s = src[e];
    int bd = d / SUBN;
    int pd = based[bd] + atomicAdd(&cntd[bd], 1);
    if (pd < SBCAP) byDst[(size_t)bd * SBCAP + pd] = ((unsigned long long)(unsigned)d << 32) | (unsigned)s;
    int bs = s / SUBN;
    int ps = bases[bs] + atomicAdd(&cnts[bs], 1);
    if (ps < SBCAP) bySrc[(size_t)bs * SBCAP + ps] = s;
  }
}

// ---- P2a: per-sub-bin histogram + scan + CSR scatter. No global atomics. ----
__global__ __launch_bounds__(1024) void k_csr_dst(
    const unsigned long long* __restrict__ byDst, const int* __restrict__ cur_d,
    int* __restrict__ csr, int* __restrict__ row_start, int* __restrict__ deg_in) {
  int q = blockIdx.x;
  int nlo = q * SUBN;
  int nhi = nlo + SUBN; if (nhi > NN) nhi = NN;
  int nloc = nhi - nlo;
  __shared__ int hist[SUBN];
  __shared__ int wsum[16];
  int tid = threadIdx.x;
  for (int i = tid; i < SUBN; i += 1024) hist[i] = 0;
  __syncthreads();
  int m = cur_d[q];
  if (m > SBCAP) m = SBCAP;
  const unsigned long long* bine = byDst + (size_t)q * SBCAP;
  for (int i = tid; i < m; i += 1024) {
    int l = (int)(bine[i] >> 32) - nlo;
    if (l >= 0 && l < nloc) atomicAdd(&hist[l], 1);
  }
  __syncthreads();
  int v = (tid < SUBN) ? hist[tid] : 0;
  int incl = v;
  int lane = tid & 63;
#pragma unroll
  for (int off = 1; off < 64; off <<= 1) {
    int t2 = __shfl_up(incl, off);
    if (lane >= off) incl += t2;
  }
  int wid = tid >> 6;
  if (lane == 63) wsum[wid] = incl;
  __syncthreads();
  if (tid == 0) {
    int run = 0;
    for (int i = 0; i < 16; ++i) { int t = wsum[i]; wsum[i] = run; run += t; }
  }
  __syncthreads();
  int excl = incl - v + wsum[wid];
  if (tid < nloc) {
    deg_in[nlo + tid] = v;
    row_start[nlo + tid] = q * SBCAP + excl;
  }
  __syncthreads();
  if (tid < SUBN) hist[tid] = excl;   // scatter cursor
  __syncthreads();
  for (int i = tid; i < m; i += 1024) {
    unsigned long long p = bine[i];
    int l = (int)(p >> 32) - nlo;
    if (l >= 0 && l < nloc) {
      int pos = atomicAdd(&hist[l], 1);
      if (pos < SBCAP) csr[(size_t)q * SBCAP + pos] = (int)(unsigned)p;
    }
  }
}

// ---- P2b: histogram-only for deg_out ----
__global__ __launch_bounds__(1024) void k_deg_src(
    const int* __restrict__ bySrc, const int* __restrict__ cur_s,
    int* __restrict__ deg_out) {
  int q = blockIdx.x;
  int nlo = q * SUBN;
  int nhi = nlo + SUBN; if (nhi > NN) nhi = NN;
  int nloc = nhi - nlo;
  __shared__ int hist[SUBN];
  int tid = threadIdx.x;
  for (int i = tid; i < SUBN; i += 1024) hist[i] = 0;
  __syncthreads();
  int m = cur_s[q];
  if (m > SBCAP) m = SBCAP;
  const int* bine = bySrc + (size_t)q * SBCAP;
  for (int i = tid; i < m; i += 1024) {
    int l = bine[i] - nlo;
    if (l >= 0 && l < nloc) atomicAdd(&hist[l], 1);
  }
  __syncthreads();
  for (int i = tid; i < nloc; i += 1024) deg_out[nlo + i] = hist[i];
}

// ---- norms ----
__global__ __launch_bounds__(256) void k_norm(
    const int* __restrict__ deg_out, const int* __restrict__ deg_in,
    float* __restrict__ out_norm, float* __restrict__ in_norm) {
  int i = blockIdx.x * 256 + threadIdx.x;
  if (i >= NN) return;
  int od = deg_out[i], idg = deg_in[i];
  out_norm[i] = od > 0 ? rsqrtf((float)od) : 0.f;
  in_norm[i]  = idg > 0 ? rsqrtf((float)idg) : 0.f;
}

// ---- aggregation: one wave per dst node, fp16 row gather, f32 accumulate ----
__global__ __launch_bounds__(256) void k_agg(
    const __half* __restrict__ x, const int* __restrict__ csr,
    const int* __restrict__ row_start, const int* __restrict__ deg_in,
    const float* __restrict__ out_norm, float* __restrict__ agg) {
  int node = blockIdx.x * 4 + (threadIdx.x >> 6);
  int lane = threadIdx.x & 63;
  if (node >= NN) return;
  int n = deg_in[node];
  const int* bk = csr + row_start[node];
  const __half2* xv = (const __half2*)x;
  float2 a0 = {0.f, 0.f}, a1 = {0.f, 0.f}, a2 = {0.f, 0.f}, a3 = {0.f, 0.f};
  for (int c0 = 0; c0 < n; c0 += 64) {
    int nn = n - c0; if (nn > 64) nn = 64;
    int sl = 0; float wl = 0.f;
    if (lane < nn) { sl = bk[c0 + lane]; wl = out_norm[sl]; }
    int j = 0;
    for (; j + 4 <= nn; j += 4) {
      int s0 = __shfl(sl, j + 0), s1 = __shfl(sl, j + 1);
      int s2 = __shfl(sl, j + 2), s3 = __shfl(sl, j + 3);
      float w0 = __shfl(wl, j + 0), w1 = __shfl(wl, j + 1);
      float w2 = __shfl(wl, j + 2), w3 = __shfl(wl, j + 3);
      float2 v0 = __half22float2(xv[(size_t)s0 * 64 + lane]);
      float2 v1 = __half22float2(xv[(size_t)s1 * 64 + lane]);
      float2 v2 = __half22float2(xv[(size_t)s2 * 64 + lane]);
      float2 v3 = __half22float2(xv[(size_t)s3 * 64 + lane]);
      a0.x += v0.x * w0; a0.y += v0.y * w0;
      a1.x += v1.x * w1; a1.y += v1.y * w1;
      a2.x += v2.x * w2; a2.y += v2.y * w2;
      a3.x += v3.x * w3; a3.y += v3.y * w3;
    }
    for (; j < nn; ++j) {
      int s0 = __shfl(sl, j);
      float w0 = __shfl(wl, j);
      float2 v0 = __half22float2(xv[(size_t)s0 * 64 + lane]);
      a0.x += v0.x * w0; a0.y += v0.y * w0;
    }
  }
  a0.x += a1.x + a2.x + a3.x;
  a0.y += a1.y + a2.y + a3.y;
  ((float2*)agg)[(size_t)node * 64 + lane] = a0;
}

// ---- MFMA GEMM: Y[i][c] = act(in_norm[i] * (A@W)[i][c] + b[c]) ----
// Split-fp16: A=A_hi+A_lo, W=W_hi+W_lo; acc = Ah*Wh + Ah*Wl + Al*Wh (f32 MFMA acc).
// POOL: instead of storing Y, compute per-row logits z[row] = y@Wc (2 cols) via
// 16-lane butterfly and store dense z[NN][2] (no atomics).
template <bool RELU, bool HOUT, bool POOL>
__global__ __launch_bounds__(256) void k_gemm_mfma(
    const float* __restrict__ A, const float* __restrict__ in_norm,
    const _Float16* __restrict__ Whi, const _Float16* __restrict__ Wlo,
    const float* __restrict__ bias, void* __restrict__ Yv,
    const float* __restrict__ Wc, float2* __restrict__ z) {
  __shared__ __align__(16) _Float16 lhi[16384];
  __shared__ __align__(16) _Float16 llo[16384];
  int tid = threadIdx.x;
  {
    const uint4* sh = (const uint4*)Whi;
    const uint4* sl = (const uint4*)Wlo;
    uint4* dh = (uint4*)lhi;
    uint4* dl = (uint4*)llo;
#pragma unroll
    for (int i = 0; i < 8; ++i) {
      dh[tid + i * 256] = sh[tid + i * 256];
      dl[tid + i * 256] = sl[tid + i * 256];
    }
  }
  __syncthreads();
  int wid = tid >> 6, lane = tid & 63;
  int row0 = blockIdx.x * 64 + wid * 16;
  int ar = row0 + (lane & 15);
  bool rv = ar < NN;
  f16x8 ahi[4], alo[4];
#pragma unroll
  for (int kk = 0; kk < 4; ++kk) {
    float v[8];
    if (rv) {
      const float4* ap = (const float4*)(A + (size_t)ar * DD + kk * 32 + ((lane >> 4) << 3));
      float4 u0 = ap[0], u1 = ap[1];
      v[0] = u0.x; v[1] = u0.y; v[2] = u0.z; v[3] = u0.w;
      v[4] = u1.x; v[5] = u1.y; v[6] = u1.z; v[7] = u1.w;
    } else {
#pragma unroll
      for (int j = 0; j < 8; ++j) v[j] = 0.f;
    }
#pragma unroll
    for (int j = 0; j < 8; ++j) {
      _Float16 h = (_Float16)v[j];
      ahi[kk][j] = h;
      alo[kk][j] = (_Float16)(v[j] - (float)h);
    }
  }
  f32x4 acc[8];
#pragma unroll
  for (int nt = 0; nt < 8; ++nt) acc[nt] = (f32x4){0.f, 0.f, 0.f, 0.f};
#pragma unroll
  for (int nt = 0; nt < 8; ++nt) {
#pragma unroll
    for (int kk = 0; kk < 4; ++kk) {
      f16x8 bh = *(const f16x8*)&lhi[(((nt * 4 + kk) * 64) + lane) * 8];
      f16x8 bl = *(const f16x8*)&llo[(((nt * 4 + kk) * 64) + lane) * 8];
      acc[nt] = __builtin_amdgcn_mfma_f32_16x16x32_f16(ahi[kk], bh, acc[nt], 0, 0, 0);
      acc[nt] = __builtin_amdgcn_mfma_f32_16x16x32_f16(ahi[kk], bl, acc[nt], 0, 0, 0);
      acc[nt] = __builtin_amdgcn_mfma_f32_16x16x32_f16(alo[kk], bh, acc[nt], 0, 0, 0);
    }
  }
  int r4 = (lane >> 4) * 4;
  int c0 = lane & 15;
  if (POOL) {
    float wc0[8], wc1[8];
#pragma unroll
    for (int nt = 0; nt < 8; ++nt) {
      int col = nt * 16 + c0;
      wc0[nt] = Wc[col * 2 + 0];
      wc1[nt] = Wc[col * 2 + 1];
    }
#pragma unroll
    for (int reg = 0; reg < 4; ++reg) {
      int row = row0 + r4 + reg;
      float inm = (row < NN) ? in_norm[row] : 0.f;
      float v0 = 0.f, v1 = 0.f;
#pragma unroll
      for (int nt = 0; nt < 8; ++nt) {
        int col = nt * 16 + c0;
        float y = acc[nt][reg] * inm + bias[col];
        if (RELU) y = fmaxf(y, 0.f);
        v0 += y * wc0[nt];
        v1 += y * wc1[nt];
      }
#pragma unroll
      for (int off = 1; off < 16; off <<= 1) {
        v0 += __shfl_xor(v0, off);
        v1 += __shfl_xor(v1, off);
      }
      if (row < NN && c0 == 0) {
        z[row] = make_float2(v0, v1);
      }
    }
  } else {
#pragma unroll
    for (int reg = 0; reg < 4; ++reg) {
      int row = row0 + r4 + reg;
      if (row < NN) {
        float inm = in_norm[row];
#pragma unroll
        for (int nt = 0; nt < 8; ++nt) {
          int col = nt * 16 + c0;
          float y = acc[nt][reg] * inm + bias[col];
          if (RELU) y = fmaxf(y, 0.f);
          if (HOUT) ((__half*)Yv)[(size_t)row * DD + col] = __float2half(y);
          else      ((float*)Yv)[(size_t)row * DD + col] = y;
        }
      }
    }
  }
}

// ---- pool: one wave per graph; segment-mean of z + bias -> out ----
__global__ __launch_bounds__(256) void k_pool2(
    const float* __restrict__ z, const int* __restrict__ gid,
    const float* __restrict__ bc, float* __restrict__ out) {
  int g = blockIdx.x * 4 + (threadIdx.x >> 6);
  int lane = threadIdx.x & 63;
  if (g >= NG) return;
  int lo, hi;
  { int a = 0, b = NN; while (a < b) { int m = (a + b) >> 1; if (gid[m] < g) a = m + 1; else b = m; } lo = a; }
  { int a = lo, b = NN; while (a < b) { int m = (a + b) >> 1; if (gid[m] <= g) a = m + 1; else b = m; } hi = a; }
  float s = 0.f;
  int col = lane & 1;
  for (int i = lo + (lane >> 1); i < hi; i += 32) s += z[i * 2 + col];
#pragma unroll
  for (int off = 32; off >= 2; off >>= 1) s += __shfl_down(s, off);
  if (lane < 2) {
    int n = hi - lo;
    out[g * 2 + lane] = s / (float)(n > 0 ? n : 1) + bc[lane];
  }
}

extern "C" void kernel_launch(void* const* d_in, const int* in_sizes, int n_in,
                              void* d_out, int out_size, void* d_ws, size_t ws_size,
                              hipStream_t stream) {
  const float* features = (const float*)d_in[0];
  const int* src = (const int*)d_in[1];
  const int* dst = (const int*)d_in[2];
  const int* gid = (const int*)d_in[3];
  const float* W1 = (const float*)d_in[4];
  const float* b1 = (const float*)d_in[5];
  const float* W2 = (const float*)d_in[6];
  const float* b2 = (const float*)d_in[7];
  const float* Wc = (const float*)d_in[8];
  const float* bc = (const float*)d_in[9];
  float* out = (float*)d_out;

  char* ws = (char*)d_ws;
  size_t off = 0;
  auto take = [&](size_t bytes) {
    char* p = ws + off;
    off = (off + bytes + 255) & ~(size_t)255;
    return p;
  };
  int* cur_d      = (int*)take(NSB * 4);
  int* cur_s      = (int*)take(NSB * 4);
  int* deg_out    = (int*)take((size_t)NN * 4);
  int* deg_in     = (int*)take((size_t)NN * 4);
  float* out_nrm  = (float*)take((size_t)NN * 4);
  float* in_nrm   = (float*)take((size_t)NN * 4);
  int* row_start  = (int*)take((size_t)NN * 4);
  float* zbuf     = (float*)take((size_t)NN * 2 * 4);
  unsigned long long* byDst = (unsigned long long*)take((size_t)NSB * SBCAP * 8);
  int* bySrc      = (int*)take((size_t)NSB * SBCAP * 4);
  int* csr        = (int*)take((size_t)NSB * SBCAP * 4);
  __half* xh      = (__half*)take((size_t)NN * DD * 2);
  __half* h1h     = (__half*)take((size_t)NN * DD * 2);
  float* bufA     = (float*)take((size_t)NN * DD * 4);
  _Float16* w1hi  = (_Float16*)take((size_t)DD * DD * 2);
  _Float16* w1lo  = (_Float16*)take((size_t)DD * DD * 2);
  _Float16* w2hi  = (_Float16*)take((size_t)DD * DD * 2);
  _Float16* w2lo  = (_Float16*)take((size_t)DD * DD * 2);

  hipMemsetAsync(cur_d, 0, NSB * 4, stream);
  hipMemsetAsync(cur_s, 0, NSB * 4, stream);

  k_f2h<<<(NN * DD / 4 + 255) / 256, 256, 0, stream>>>((const float4*)features, (uint2*)xh, NN * DD / 4);
  k_wsplit<<<8, 256, 0, stream>>>(W1, w1hi, w1lo);
  k_wsplit<<<8, 256, 0, stream>>>(W2, w2hi, w2lo);
  k_bin<<<NB1, 256, 0, stream>>>(src, dst, cur_d, cur_s, byDst, bySrc);
  k_csr_dst<<<NSB, 1024, 0, stream>>>(byDst, cur_d, csr, row_start, deg_in);
  k_deg_src<<<NSB, 1024, 0, stream>>>(bySrc, cur_s, deg_out);
  k_norm<<<(NN + 255) / 256, 256, 0, stream>>>(deg_out, deg_in, out_nrm, in_nrm);

  // layer 1: agg(xh) -> bufA ; mfma-gemm+relu -> h1h (fp16)
  k_agg<<<(NN + 3) / 4, 256, 0, stream>>>(xh, csr, row_start, deg_in, out_nrm, bufA);
  k_gemm_mfma<true, true, false><<<(NN + 63) / 64, 256, 0, stream>>>(
      bufA, in_nrm, w1hi, w1lo, b1, h1h, nullptr, nullptr);

  // layer 2: agg(h1h) -> bufA ; mfma-gemm + fused classifier logits -> zbuf
  k_agg<<<(NN + 3) / 4, 256, 0, stream>>>(h1h, csr, row_start, deg_in, out_nrm, bufA);
  k_gemm_mfma<false, false, true><<<(NN + 63) / 64, 256, 0, stream>>>(
      bufA, in_nrm, w2hi, w2lo, b2, nullptr, Wc, (float2*)zbuf);

  // segment mean-pool + bias
  k_pool2<<<(NG + 3) / 4, 256, 0, stream>>>(zbuf, gid, bc, out);
}